// Round 4
// baseline (214.780 us; speedup 1.0000x reference)
//
#include <hip/hip_runtime.h>
#include <hip/hip_bf16.h>

typedef __attribute__((ext_vector_type(8))) short short8;
typedef __attribute__((ext_vector_type(4))) float f32x4;

#define SEPS   0.05f
#define KC     28.853900817779268f     // log2(e)/eps
#define EPSLN2 0.034657359027997264f   // eps*ln2 = 1/KC
#define LN2    0.6931471805599453f

__device__ __forceinline__ unsigned short bf16_rne(float f) {
  unsigned int u = __float_as_uint(f);
  unsigned int r = (u + 0x7fffu + ((u >> 16) & 1u)) >> 16;
  return (unsigned short)r;
}

// ---------------- K1: per-(b,m) chunk [640 c][64 x] f32 -> l2norm over c -> bf16 [64 x][640 c]
// Single-pass, register-resident: each of 1024 threads owns (4 consecutive x) x (1 c per
// 64-c tile) = 10 float4 held in registers. No global re-read. Query and proto chunks
// handled by one merged launch (blk < 600 -> query, else proto).
__global__ __launch_bounds__(1024) void norm_pack(const float* __restrict__ q,
                                                  const float* __restrict__ p,
                                                  unsigned short* __restrict__ qo,
                                                  unsigned short* __restrict__ po) {
  int blk = blockIdx.x;
  const float* src;
  unsigned short* dst;
  if (blk < 600) { src = q + (size_t)blk * 40960; dst = qo + (size_t)blk * 40960; }
  else           { src = p + (size_t)(blk - 600) * 40960; dst = po + (size_t)(blk - 600) * 40960; }

  int t = threadIdx.x;
  int xg = t & 15, cg = t >> 4;   // xg: x-quad 0..15, cg: c-row 0..63
  int x4 = xg * 4;

  // load all 10 c-tiles' worth: v[k] = src[(cg + 64k)][x4..x4+3]
  f32x4 v[10];
  float ss[4] = {0.f, 0.f, 0.f, 0.f};
  #pragma unroll
  for (int k = 0; k < 10; ++k) {
    v[k] = *(const f32x4*)(src + (size_t)(cg + 64 * k) * 64 + x4);
    #pragma unroll
    for (int j = 0; j < 4; ++j) ss[j] = fmaf(v[k][j], v[k][j], ss[j]);
  }

  // reduce sumsq over c: intra-wave (lanes l, l^16, l^32, l^48 share xg) then cross-wave LDS
  #pragma unroll
  for (int j = 0; j < 4; ++j) {
    ss[j] += __shfl_xor(ss[j], 16, 64);
    ss[j] += __shfl_xor(ss[j], 32, 64);
  }
  __shared__ float red[16][64];
  __shared__ float scale_s[64];
  int wv = t >> 6, ln = t & 63;
  if (ln < 16) {
    #pragma unroll
    for (int j = 0; j < 4; ++j) red[wv][ln * 4 + j] = ss[j];
  }
  __syncthreads();
  if (t < 64) {
    float s = 0.f;
    #pragma unroll
    for (int w2 = 0; w2 < 16; ++w2) s += red[w2][t];
    scale_s[t] = 1.0f / fmaxf(sqrtf(s), 1e-12f);  // matches x/max(||x||,eps)
  }
  __syncthreads();
  float sc[4];
  #pragma unroll
  for (int j = 0; j < 4; ++j) sc[j] = scale_s[x4 + j];

  // transpose+pack: 5 rounds x 2 c-tiles via padded f32 LDS tiles (banks 2-way = free)
  __shared__ float tile[2][64][65];
  int t9 = t & 511, th = t >> 9;
  int pr = t9 >> 3, pc = (t9 & 7) * 8;
  #pragma unroll
  for (int rd = 0; rd < 5; ++rd) {
    #pragma unroll
    for (int h = 0; h < 2; ++h) {
      f32x4 u = v[rd * 2 + h];
      #pragma unroll
      for (int j = 0; j < 4; ++j) tile[h][x4 + j][cg] = u[j] * sc[j];
    }
    __syncthreads();
    unsigned int pk[4];
    #pragma unroll
    for (int k2 = 0; k2 < 4; ++k2) {
      unsigned int lo = bf16_rne(tile[th][pr][pc + 2 * k2]);
      unsigned int hi = bf16_rne(tile[th][pr][pc + 2 * k2 + 1]);
      pk[k2] = lo | (hi << 16);
    }
    *(uint4*)(dst + (size_t)pr * 640 + (rd * 2 + th) * 64 + pc) = make_uint4(pk[0], pk[1], pk[2], pk[3]);
    __syncthreads();
  }
}

// ---------------- K2: per-(b,q,w) 64x64x640 bf16 MFMA GEMM -> sim f32
// A: [b*75+q][64 x][640 c] bf16, B: [b*5+w][64 y][640 c] bf16
// C: sim[b,q][x][w*64+y] f32 (row stride 320)
__global__ __launch_bounds__(64) void gemm64(const unsigned short* __restrict__ A,
                                             const unsigned short* __restrict__ B,
                                             float* __restrict__ C) {
  __shared__ alignas(16) unsigned short As[2][64][32];
  __shared__ alignas(16) unsigned short Bs[2][64][32];
  int blk = blockIdx.x;
  int w = blk % 5;
  int bq = blk / 5;
  int b = bq / 75;
  const unsigned short* Ab = A + (size_t)bq * 40960;
  const unsigned short* Bb = B + (size_t)(b * 5 + w) * 40960;
  float* Cb = C + (size_t)bq * 20480 + w * 64;

  int l = threadIdx.x;
  int lrow = l >> 2, lslot = l & 3;
  int fr = l & 15, k8 = l >> 4;
  int soff = ((k8 ^ (fr & 3)) << 4);  // swizzled 16B slot byte offset within 64B row

  f32x4 acc[4][4];
  #pragma unroll
  for (int i = 0; i < 4; ++i)
    #pragma unroll
    for (int j = 0; j < 4; ++j)
      acc[i][j] = (f32x4){0.f, 0.f, 0.f, 0.f};

  // stage one K-chunk (32 k's) of A and B into LDS buffer `buf`.
  // LDS dest is linear (wave base + lane*16B); source address carries the
  // inverse XOR swizzle so swizzled reads below see correct data.
  auto stage = [&](int buf, int k0) {
    #pragma unroll
    for (int t = 0; t < 4; ++t) {
      int row = t * 16 + lrow;
      int sl = lslot ^ (row & 3);
      __builtin_amdgcn_global_load_lds(
          (const __attribute__((address_space(1))) unsigned int*)(Ab + (size_t)row * 640 + k0 + sl * 8),
          (__attribute__((address_space(3))) unsigned int*)&As[buf][t * 16][0], 16, 0, 0);
      __builtin_amdgcn_global_load_lds(
          (const __attribute__((address_space(1))) unsigned int*)(Bb + (size_t)row * 640 + k0 + sl * 8),
          (__attribute__((address_space(3))) unsigned int*)&Bs[buf][t * 16][0], 16, 0, 0);
    }
  };

  stage(0, 0);
  #pragma unroll 1
  for (int s = 0; s < 20; ++s) {
    int buf = s & 1;
    if (s < 19) {
      stage(buf ^ 1, (s + 1) * 32);
      asm volatile("s_waitcnt vmcnt(8)" ::: "memory");  // current buf's 8 loads done
    } else {
      asm volatile("s_waitcnt vmcnt(0)" ::: "memory");
    }
    short8 aF[4], bF[4];
    #pragma unroll
    for (int mi = 0; mi < 4; ++mi) {
      aF[mi] = *(const short8*)((const char*)&As[buf][0][0] + ((mi * 16 + fr) * 64 + soff));
      bF[mi] = *(const short8*)((const char*)&Bs[buf][0][0] + ((mi * 16 + fr) * 64 + soff));
    }
    #pragma unroll
    for (int mi = 0; mi < 4; ++mi)
      #pragma unroll
      for (int ni = 0; ni < 4; ++ni)
        acc[mi][ni] = __builtin_amdgcn_mfma_f32_16x16x32_bf16(aF[mi], bF[ni], acc[mi][ni], 0, 0, 0);
  }

  int crow = (k8) * 4;  // C/D layout: col = lane&15, row = (lane>>4)*4 + reg
  #pragma unroll
  for (int mi = 0; mi < 4; ++mi)
    #pragma unroll
    for (int ni = 0; ni < 4; ++ni)
      #pragma unroll
      for (int r = 0; r < 4; ++r)
        Cb[(size_t)(mi * 16 + crow + r) * 320 + (ni * 16 + fr)] = acc[mi][ni][r];
}

// ---------------- K3: Sinkhorn (50 iters) + logit, TWO problems per wave
// Multiplicative-domain Sinkhorn (E = exp(-c/eps) precomputed in registers; u/v
// updates are pure fmac matvecs). Broadcast via v_readlane (round-2 proven). The
// serial u->v chain is latency-bound at ~3 waves/SIMD, so each wave interleaves
// TWO independent (b,q,w) problems: 8 accumulator chains + 2 readlane streams
// double the issue density at identical aggregate instruction count. Erow is
// gathered directly from global (L2/L3-resident, bit-identical values) -- no LDS.
__device__ __forceinline__ float rl(float v, int lane) {
  return __int_as_float(__builtin_amdgcn_readlane(__float_as_int(v), lane));
}
__device__ __forceinline__ float wredsum(float v) {
  #pragma unroll
  for (int m = 1; m < 64; m <<= 1) v += __shfl_xor(v, m, 64);
  return v;
}

__global__ __launch_bounds__(64, 1) void sinkhorn_k(const float* __restrict__ sim,
                                                    float* __restrict__ out) {
  int pb = blockIdx.x;
  int p0 = pb * 2, p1 = p0 + 1;
  const float* SA = sim + (size_t)(p0 / 5) * 20480 + (p0 % 5) * 64;
  const float* SB = sim + (size_t)(p1 / 5) * 20480 + (p1 % 5) * 64;
  int l = threadIdx.x;

  // Ecol: lane l holds column l of E (coalesced col loads).
  float EcolA[64], EcolB[64];
  float colsumA = 0.f, colsumB = 0.f;
  #pragma unroll
  for (int r = 0; r < 64; ++r) {
    float va = SA[r * 320 + l];
    float vb = SB[r * 320 + l];
    colsumA += va;
    colsumB += vb;
    EcolA[r] = __builtin_amdgcn_exp2f(-KC * (1.0f - va));
    EcolB[r] = __builtin_amdgcn_exp2f(-KC * (1.0f - vb));
  }
  // Erow: lane l holds row l of E (vectorized row gather, L2/L3-hit).
  float ErowA[64], ErowB[64];
  float rowsumA = 0.f, rowsumB = 0.f;
  #pragma unroll
  for (int jc = 0; jc < 16; ++jc) {
    f32x4 ra = *(const f32x4*)(SA + (size_t)l * 320 + jc * 4);
    f32x4 rb = *(const f32x4*)(SB + (size_t)l * 320 + jc * 4);
    #pragma unroll
    for (int k = 0; k < 4; ++k) {
      float ca = 1.0f - ra[k];
      float cb = 1.0f - rb[k];
      rowsumA += ca;
      rowsumB += cb;
      ErowA[jc * 4 + k] = __builtin_amdgcn_exp2f(-KC * ca);
      ErowB[jc * 4 + k] = __builtin_amdgcn_exp2f(-KC * cb);
    }
  }

  // masses: weight_1 = relu(mean_y sim)+1e-3 (rows), weight_2' = relu(mean_x sim)+1e-3 (cols)
  float w1A = fmaxf(1.0f - rowsumA * (1.0f / 64.0f), 0.f) + 0.001f;
  float w1B = fmaxf(1.0f - rowsumB * (1.0f / 64.0f), 0.f) + 0.001f;
  float w2A = fmaxf(colsumA * (1.0f / 64.0f), 0.f) + 0.001f;
  float w2B = fmaxf(colsumB * (1.0f / 64.0f), 0.f) + 0.001f;
  float amassA = w1A * __builtin_amdgcn_rcpf(wredsum(w1A));
  float amassB = w1B * __builtin_amdgcn_rcpf(wredsum(w1B));
  float bmassA = w2A * __builtin_amdgcn_rcpf(wredsum(w2A));
  float bmassB = w2B * __builtin_amdgcn_rcpf(wredsum(w2B));

  const float UMIN = 1.80485139e-35f;   // exp(-80) == exp(-4/eps): the f,g +-4 clamp
  const float UMAX = 5.54062238e+34f;   // exp(+80)

  float uuA = 0.f, vvA = 1.0f;          // g0 = 0 -> v0 = 1
  float uuB = 0.f, vvB = 1.0f;
  #pragma unroll 1
  for (int it = 0; it < 50; ++it) {
    float sA0 = 1e-37f, sA1 = 0.f, sA2 = 0.f, sA3 = 0.f;
    float sB0 = 1e-37f, sB1 = 0.f, sB2 = 0.f, sB3 = 0.f;
    #pragma unroll
    for (int j = 0; j < 64; j += 4) {
      sA0 = fmaf(ErowA[j],     rl(vvA, j),     sA0);
      sB0 = fmaf(ErowB[j],     rl(vvB, j),     sB0);
      sA1 = fmaf(ErowA[j + 1], rl(vvA, j + 1), sA1);
      sB1 = fmaf(ErowB[j + 1], rl(vvB, j + 1), sB1);
      sA2 = fmaf(ErowA[j + 2], rl(vvA, j + 2), sA2);
      sB2 = fmaf(ErowB[j + 2], rl(vvB, j + 2), sB2);
      sA3 = fmaf(ErowA[j + 3], rl(vvA, j + 3), sA3);
      sB3 = fmaf(ErowB[j + 3], rl(vvB, j + 3), sB3);
    }
    float sA = (sA0 + sA1) + (sA2 + sA3);
    float sB = (sB0 + sB1) + (sB2 + sB3);
    uuA = fminf(fmaxf(amassA * __builtin_amdgcn_rcpf(sA), UMIN), UMAX);
    uuB = fminf(fmaxf(amassB * __builtin_amdgcn_rcpf(sB), UMIN), UMAX);

    float tA0 = 1e-37f, tA1 = 0.f, tA2 = 0.f, tA3 = 0.f;
    float tB0 = 1e-37f, tB1 = 0.f, tB2 = 0.f, tB3 = 0.f;
    #pragma unroll
    for (int i = 0; i < 64; i += 4) {
      tA0 = fmaf(EcolA[i],     rl(uuA, i),     tA0);
      tB0 = fmaf(EcolB[i],     rl(uuB, i),     tB0);
      tA1 = fmaf(EcolA[i + 1], rl(uuA, i + 1), tA1);
      tB1 = fmaf(EcolB[i + 1], rl(uuB, i + 1), tB1);
      tA2 = fmaf(EcolA[i + 2], rl(uuA, i + 2), tA2);
      tB2 = fmaf(EcolB[i + 2], rl(uuB, i + 2), tB2);
      tA3 = fmaf(EcolA[i + 3], rl(uuA, i + 3), tA3);
      tB3 = fmaf(EcolB[i + 3], rl(uuB, i + 3), tB3);
    }
    float tA = (tA0 + tA1) + (tA2 + tA3);
    float tB = (tB0 + tB1) + (tB2 + tB3);
    vvA = fminf(fmaxf(bmassA * __builtin_amdgcn_rcpf(tA), UMIN), UMAX);
    vvB = fminf(fmaxf(bmassB * __builtin_amdgcn_rcpf(tB), UMIN), UMAX);
  }

  // logits = 12.5 * sum_ij (1 - c_ij) * u_i v_j E_ij ; recover c = -eps*ln2*log2(E)
  float a1A = 0.f, a2A = 0.f, a1B = 0.f, a2B = 0.f;
  #pragma unroll
  for (int j = 0; j < 64; ++j) {
    float eA = fminf((uuA * ErowA[j]) * rl(vvA, j), 1.32922800e36f);  // 2^120 guard parity
    float eB = fminf((uuB * ErowB[j]) * rl(vvB, j), 1.32922800e36f);
    float cA = -EPSLN2 * __builtin_amdgcn_logf(ErowA[j]);
    float cB = -EPSLN2 * __builtin_amdgcn_logf(ErowB[j]);
    a1A += eA;
    a2A = fmaf(cA, eA, a2A);
    a1B += eB;
    a2B = fmaf(cB, eB, a2B);
  }
  float totA = wredsum(a1A - a2A);
  float totB = wredsum(a1B - a2B);
  if (l == 0) {
    out[p0] = 12.5f * totA;
    out[p1] = 12.5f * totB;
  }
}

extern "C" void kernel_launch(void* const* d_in, const int* in_sizes, int n_in,
                              void* d_out, int out_size, void* d_ws, size_t ws_size,
                              hipStream_t stream) {
  const float* query = (const float*)d_in[0];
  const float* proto = (const float*)d_in[1];
  float* out = (float*)d_out;
  char* ws = (char*)d_ws;

  const size_t A_OFF = 0;                  // 8*75*64*640*2  = 49,152,000
  const size_t B_OFF = 49152000;           // 8*5*64*640*2   =  3,276,800
  const size_t S_OFF = 52428800;           // 8*75*5*64*64*4 = 49,152,000
  if (ws_size < 101580800ull) return;      // loud failure rather than OOB

  unsigned short* Abf = (unsigned short*)(ws + A_OFF);
  unsigned short* Bbf = (unsigned short*)(ws + B_OFF);
  float* simbuf = (float*)(ws + S_OFF);

  norm_pack<<<640, 1024, 0, stream>>>(query, proto, Abf, Bbf);  // 600 query + 40 proto chunks
  gemm64<<<3000, 64, 0, stream>>>(Abf, Bbf, simbuf);
  sinkhorn_k<<<1500, 64, 0, stream>>>(simbuf, out);             // 2 problems per wave
}

// Round 5
// 121.641 us; speedup vs baseline: 1.7657x; 1.7657x over previous
//
#include <hip/hip_runtime.h>
#include <hip/hip_bf16.h>

typedef __attribute__((ext_vector_type(8))) short short8;
typedef __attribute__((ext_vector_type(4))) float f32x4;

#define SEPS   0.05f
#define KC     28.853900817779268f     // log2(e)/eps
#define EPSLN2 0.034657359027997264f   // eps*ln2 = 1/KC
#define LN2    0.6931471805599453f

__device__ __forceinline__ unsigned short bf16_rne(float f) {
  unsigned int u = __float_as_uint(f);
  unsigned int r = (u + 0x7fffu + ((u >> 16) & 1u)) >> 16;
  return (unsigned short)r;
}

// ---------------- K1: per-(b,m) chunk [640 c][64 x] f32 -> l2norm over c -> bf16 [64 x][640 c]
// Single-pass, register-resident: each of 1024 threads owns (4 consecutive x) x (1 c per
// 64-c tile) = 10 float4 held in registers. No global re-read. Query and proto chunks
// handled by one merged launch (blk < 600 -> query, else proto).
__global__ __launch_bounds__(1024) void norm_pack(const float* __restrict__ q,
                                                  const float* __restrict__ p,
                                                  unsigned short* __restrict__ qo,
                                                  unsigned short* __restrict__ po) {
  int blk = blockIdx.x;
  const float* src;
  unsigned short* dst;
  if (blk < 600) { src = q + (size_t)blk * 40960; dst = qo + (size_t)blk * 40960; }
  else           { src = p + (size_t)(blk - 600) * 40960; dst = po + (size_t)(blk - 600) * 40960; }

  int t = threadIdx.x;
  int xg = t & 15, cg = t >> 4;   // xg: x-quad 0..15, cg: c-row 0..63
  int x4 = xg * 4;

  // load all 10 c-tiles' worth: v[k] = src[(cg + 64k)][x4..x4+3]
  f32x4 v[10];
  float ss[4] = {0.f, 0.f, 0.f, 0.f};
  #pragma unroll
  for (int k = 0; k < 10; ++k) {
    v[k] = *(const f32x4*)(src + (size_t)(cg + 64 * k) * 64 + x4);
    #pragma unroll
    for (int j = 0; j < 4; ++j) ss[j] = fmaf(v[k][j], v[k][j], ss[j]);
  }

  // reduce sumsq over c: intra-wave (lanes l, l^16, l^32, l^48 share xg) then cross-wave LDS
  #pragma unroll
  for (int j = 0; j < 4; ++j) {
    ss[j] += __shfl_xor(ss[j], 16, 64);
    ss[j] += __shfl_xor(ss[j], 32, 64);
  }
  __shared__ float red[16][64];
  __shared__ float scale_s[64];
  int wv = t >> 6, ln = t & 63;
  if (ln < 16) {
    #pragma unroll
    for (int j = 0; j < 4; ++j) red[wv][ln * 4 + j] = ss[j];
  }
  __syncthreads();
  if (t < 64) {
    float s = 0.f;
    #pragma unroll
    for (int w2 = 0; w2 < 16; ++w2) s += red[w2][t];
    scale_s[t] = 1.0f / fmaxf(sqrtf(s), 1e-12f);  // matches x/max(||x||,eps)
  }
  __syncthreads();
  float sc[4];
  #pragma unroll
  for (int j = 0; j < 4; ++j) sc[j] = scale_s[x4 + j];

  // transpose+pack: 5 rounds x 2 c-tiles via padded f32 LDS tiles (banks 2-way = free)
  __shared__ float tile[2][64][65];
  int t9 = t & 511, th = t >> 9;
  int pr = t9 >> 3, pc = (t9 & 7) * 8;
  #pragma unroll
  for (int rd = 0; rd < 5; ++rd) {
    #pragma unroll
    for (int h = 0; h < 2; ++h) {
      f32x4 u = v[rd * 2 + h];
      #pragma unroll
      for (int j = 0; j < 4; ++j) tile[h][x4 + j][cg] = u[j] * sc[j];
    }
    __syncthreads();
    unsigned int pk[4];
    #pragma unroll
    for (int k2 = 0; k2 < 4; ++k2) {
      unsigned int lo = bf16_rne(tile[th][pr][pc + 2 * k2]);
      unsigned int hi = bf16_rne(tile[th][pr][pc + 2 * k2 + 1]);
      pk[k2] = lo | (hi << 16);
    }
    *(uint4*)(dst + (size_t)pr * 640 + (rd * 2 + th) * 64 + pc) = make_uint4(pk[0], pk[1], pk[2], pk[3]);
    __syncthreads();
  }
}

// ---------------- K2: fused per-(b,q,w) {64x64x640 bf16 MFMA GEMM -> cost in LDS ->
// multiplicative Sinkhorn (50 iters) -> logit}. Single wave per block: no barriers,
// DS-pipe in-order gives all LDS ordering. The As/Bs staging LDS is dead after the
// K-loop and is reused as the 64x64 cost matrix Cm (round-2 swizzled layout), killing
// the 49 MB sim write + 24 MB re-fetch + one kernel launch. Sinkhorn core is the
// proven round-2 readlane version, bit-identical E values.
__device__ __forceinline__ float rl(float v, int lane) {
  return __int_as_float(__builtin_amdgcn_readlane(__float_as_int(v), lane));
}
__device__ __forceinline__ float wredsum(float v) {
  #pragma unroll
  for (int m = 1; m < 64; m <<= 1) v += __shfl_xor(v, m, 64);
  return v;
}

__global__ __launch_bounds__(64, 2) void gemm_sink(const unsigned short* __restrict__ A,
                                                   const unsigned short* __restrict__ B,
                                                   float* __restrict__ out) {
  __shared__ alignas(16) char sh[16384];
  unsigned short (*As)[64][32] = (unsigned short (*)[64][32])sh;          // [2][64][32]
  unsigned short (*Bs)[64][32] = (unsigned short (*)[64][32])(sh + 8192); // [2][64][32]
  float* Cm = (float*)sh;  // 4096 f32, reused after GEMM phase

  int blk = blockIdx.x;
  int w = blk % 5;
  int bq = blk / 5;
  int b = bq / 75;
  const unsigned short* Ab = A + (size_t)bq * 40960;
  const unsigned short* Bb = B + (size_t)(b * 5 + w) * 40960;

  int l = threadIdx.x;
  int lrow = l >> 2, lslot = l & 3;
  int fr = l & 15, k8 = l >> 4;
  int i31 = l & 31;
  int soff = ((k8 ^ (fr & 3)) << 4);  // swizzled 16B slot byte offset within 64B row

  f32x4 acc[4][4];
  #pragma unroll
  for (int i = 0; i < 4; ++i)
    #pragma unroll
    for (int j = 0; j < 4; ++j)
      acc[i][j] = (f32x4){0.f, 0.f, 0.f, 0.f};

  // stage one K-chunk (32 k's) of A and B into LDS buffer `buf`.
  // LDS dest is linear (wave base + lane*16B); source address carries the
  // inverse XOR swizzle so swizzled reads below see correct data.
  auto stage = [&](int buf, int k0) {
    #pragma unroll
    for (int t = 0; t < 4; ++t) {
      int row = t * 16 + lrow;
      int sl = lslot ^ (row & 3);
      __builtin_amdgcn_global_load_lds(
          (const __attribute__((address_space(1))) unsigned int*)(Ab + (size_t)row * 640 + k0 + sl * 8),
          (__attribute__((address_space(3))) unsigned int*)&As[buf][t * 16][0], 16, 0, 0);
      __builtin_amdgcn_global_load_lds(
          (const __attribute__((address_space(1))) unsigned int*)(Bb + (size_t)row * 640 + k0 + sl * 8),
          (__attribute__((address_space(3))) unsigned int*)&Bs[buf][t * 16][0], 16, 0, 0);
    }
  };

  stage(0, 0);
  #pragma unroll 1
  for (int s = 0; s < 20; ++s) {
    int buf = s & 1;
    if (s < 19) {
      stage(buf ^ 1, (s + 1) * 32);
      asm volatile("s_waitcnt vmcnt(8)" ::: "memory");  // current buf's 8 loads done
    } else {
      asm volatile("s_waitcnt vmcnt(0)" ::: "memory");  // also: all global_load_lds retired
    }
    short8 aF[4], bF[4];
    #pragma unroll
    for (int mi = 0; mi < 4; ++mi) {
      aF[mi] = *(const short8*)((const char*)&As[buf][0][0] + ((mi * 16 + fr) * 64 + soff));
      bF[mi] = *(const short8*)((const char*)&Bs[buf][0][0] + ((mi * 16 + fr) * 64 + soff));
    }
    #pragma unroll
    for (int mi = 0; mi < 4; ++mi)
      #pragma unroll
      for (int ni = 0; ni < 4; ++ni)
        acc[mi][ni] = __builtin_amdgcn_mfma_f32_16x16x32_bf16(aF[mi], bF[ni], acc[mi][ni], 0, 0, 0);
  }

  // ---- transition: cost = 1 - sim into Cm (swizzled [row][col^(row&31)]), reusing
  // the staging LDS. DS pipe is in-order per wave, so the prior ds_reads see old data
  // and the reads below see the new; one lgkmcnt(0) drains the writes.
  int crow = k8 * 4;  // C/D layout: col = lane&15, row = (lane>>4)*4 + reg
  #pragma unroll
  for (int mi = 0; mi < 4; ++mi)
    #pragma unroll
    for (int ni = 0; ni < 4; ++ni)
      #pragma unroll
      for (int r = 0; r < 4; ++r) {
        int row = mi * 16 + crow + r;
        int col = ni * 16 + fr;
        Cm[row * 64 + (col ^ (row & 31))] = 1.0f - acc[mi][ni][r];
      }
  asm volatile("s_waitcnt lgkmcnt(0)" ::: "memory");
  __builtin_amdgcn_sched_barrier(0);

  // ---- sinkhorn init (round-2 structure, source = Cm instead of global sim)
  float colsum = 0.f;
  float Ecol[64];
  #pragma unroll
  for (int r = 0; r < 64; ++r) {
    float c = Cm[r * 64 + (l ^ (r & 31))];
    colsum += (1.0f - c);
    Ecol[r] = __builtin_amdgcn_exp2f(-KC * c);
  }
  float rowsum = 0.f;
  float Erow[64];
  #pragma unroll
  for (int j = 0; j < 64; ++j) {
    float c = Cm[l * 64 + (j ^ i31)];
    rowsum += c;
    Erow[j] = __builtin_amdgcn_exp2f(-KC * c);
  }

  // masses: weight_1 = relu(mean_y sim)+1e-3 (rows), weight_2' = relu(mean_x sim)+1e-3 (cols)
  float w1 = fmaxf(1.0f - rowsum * (1.0f / 64.0f), 0.f) + 0.001f;
  float w2 = fmaxf(colsum * (1.0f / 64.0f), 0.f) + 0.001f;
  float amass = w1 * __builtin_amdgcn_rcpf(wredsum(w1));
  float bmass = w2 * __builtin_amdgcn_rcpf(wredsum(w2));

  const float UMIN = 1.80485139e-35f;   // exp(-80) == exp(-4/eps): the f,g +-4 clamp
  const float UMAX = 5.54062238e+34f;   // exp(+80)

  float uu = 0.f, vv = 1.0f;            // g0 = 0 -> v0 = 1
  #pragma unroll 1
  for (int it = 0; it < 50; ++it) {
    float s0 = 1e-37f, s1 = 0.f, s2 = 0.f, s3 = 0.f;
    #pragma unroll
    for (int j = 0; j < 64; j += 4) {
      s0 = fmaf(Erow[j],     rl(vv, j),     s0);
      s1 = fmaf(Erow[j + 1], rl(vv, j + 1), s1);
      s2 = fmaf(Erow[j + 2], rl(vv, j + 2), s2);
      s3 = fmaf(Erow[j + 3], rl(vv, j + 3), s3);
    }
    float s = (s0 + s1) + (s2 + s3);
    uu = fminf(fmaxf(amass * __builtin_amdgcn_rcpf(s), UMIN), UMAX);

    float t0 = 1e-37f, t1 = 0.f, t2 = 0.f, t3 = 0.f;
    #pragma unroll
    for (int i = 0; i < 64; i += 4) {
      t0 = fmaf(Ecol[i],     rl(uu, i),     t0);
      t1 = fmaf(Ecol[i + 1], rl(uu, i + 1), t1);
      t2 = fmaf(Ecol[i + 2], rl(uu, i + 2), t2);
      t3 = fmaf(Ecol[i + 3], rl(uu, i + 3), t3);
    }
    float t = (t0 + t1) + (t2 + t3);
    vv = fminf(fmaxf(bmass * __builtin_amdgcn_rcpf(t), UMIN), UMAX);
  }

  // logits = 12.5 * sum_ij (1 - c_ij) * u_i v_j E_ij ; recover c = -eps*ln2*log2(E)
  float a1 = 0.f, a2 = 0.f;
  #pragma unroll
  for (int j = 0; j < 64; ++j) {
    float e = fminf((uu * Erow[j]) * rl(vv, j), 1.32922800e36f);  // 2^120 guard parity
    float c = -EPSLN2 * __builtin_amdgcn_logf(Erow[j]);
    a1 += e;
    a2 = fmaf(c, e, a2);
  }
  float tot = wredsum(a1 - a2);
  if (l == 0) out[blk] = 12.5f * tot;
}

extern "C" void kernel_launch(void* const* d_in, const int* in_sizes, int n_in,
                              void* d_out, int out_size, void* d_ws, size_t ws_size,
                              hipStream_t stream) {
  const float* query = (const float*)d_in[0];
  const float* proto = (const float*)d_in[1];
  float* out = (float*)d_out;
  char* ws = (char*)d_ws;

  const size_t A_OFF = 0;                  // 8*75*64*640*2  = 49,152,000
  const size_t B_OFF = 49152000;           // 8*5*64*640*2   =  3,276,800
  if (ws_size < 52428800ull) return;       // loud failure rather than OOB

  unsigned short* Abf = (unsigned short*)(ws + A_OFF);
  unsigned short* Bbf = (unsigned short*)(ws + B_OFF);

  norm_pack<<<640, 1024, 0, stream>>>(query, proto, Abf, Bbf);  // 600 query + 40 proto chunks
  gemm_sink<<<3000, 64, 0, stream>>>(Abf, Bbf, out);            // fused GEMM + Sinkhorn
}